// Round 3
// baseline (205.516 us; speedup 1.0000x reference)
//
#include <hip/hip_runtime.h>

typedef unsigned short u16;
typedef unsigned int u32;
typedef short bf16x8 __attribute__((ext_vector_type(8)));
typedef float f32x4 __attribute__((ext_vector_type(4)));
typedef u32 u32x4 __attribute__((ext_vector_type(4)));

#define MFMA16(a, b, c) __builtin_amdgcn_mfma_f32_16x16x32_bf16((a), (b), (c), 0, 0, 0)

__device__ __forceinline__ u16 f2bf(float f) {
  u32 u = __builtin_bit_cast(u32, f);
  u += 0x7FFFu + ((u >> 16) & 1u);
  return (u16)(u >> 16);
}
// packed f32x2 -> bf16x2; HW builtin when available, software RNE otherwise
__device__ __forceinline__ u32 pk2bf(float a, float b) {
#if __has_builtin(__builtin_amdgcn_cvt_pk_bf16_f32)
  auto v = __builtin_amdgcn_cvt_pk_bf16_f32(a, b);
  return __builtin_bit_cast(u32, v);
#else
  return (u32)f2bf(a) | ((u32)f2bf(b) << 16);
#endif
}

// ws byte offsets
#define WS_MGF   0         // bf16 [8 jt][64 lane][8 j]      B-frags of M^T   (8192 B)
#define WS_WT1F  8192      // bf16 [8 ot][2 h][4 ks][64][8]  B-frags of Wp1   (65536 B)
#define WS_WT2F  73728     // bf16 [8 mt][4 h][4 ks][64][8]  A-frags of Wp2^T (131072 B)
#define WS_B1    204800    // f32 [128]  bias1 + T0-fold
#define WS_B2    205312    // f32 [128]  bias2 + T0-fold

// NOTE on element order (kc-permutation): within each 32-wide kc chunk, the
// fragment element at (reader lane q, elem j) holds channel
//   c_local = (j>>2)*16 + q*4 + (j&3)
// chosen so the G1 producer's 8 outputs per lane are CONTIGUOUS in LDS
// (one ds_write_b128). WT1F/WT2F below are built with the same order.
__global__ void prep_kernel(const float* __restrict__ adj,
                            const float* __restrict__ adj_bias,
                            const float* __restrict__ w1,
                            const float* __restrict__ b1,
                            const float* __restrict__ w2,
                            const float* __restrict__ b2,
                            char* __restrict__ ws) {
  const int tid = threadIdx.x;
  if (blockIdx.x == 0) {
    __shared__ float sa[1024], Ls[1024], L2s[1024], L3s[1024], sdre[32];
    float bias = adj_bias[0];
    for (int i = tid; i < 1024; i += 256) sa[i] = fmaxf(adj[i] + bias, 0.0f);
    __syncthreads();
    if (tid < 32) {
      float s = 0.0f;
      for (int c = 0; c < 32; ++c) s += sa[tid * 32 + c];
      sdre[tid] = 1.0f / sqrtf(s + 1e-5f);
    }
    __syncthreads();
    for (int i = tid; i < 1024; i += 256) {
      int n = i >> 5, c = i & 31;
      Ls[i] = (n == c ? 1.0f : 0.0f) - sdre[n] * sa[i] * sdre[c];
    }
    __syncthreads();
    for (int i = tid; i < 1024; i += 256) {
      int r = i >> 5, c = i & 31;
      float s = 0.0f;
      for (int m = 0; m < 32; ++m) s += Ls[r * 32 + m] * Ls[m * 32 + c];
      L2s[i] = s;
    }
    __syncthreads();
    for (int i = tid; i < 1024; i += 256) {
      int r = i >> 5, c = i & 31;
      float s = 0.0f;
      for (int m = 0; m < 32; ++m) s += L2s[r * 32 + m] * Ls[m * 32 + c];
      L3s[i] = s;
    }
    __syncthreads();
    // M stacked [128x32]: rows 0-31 I, 32-63 L, 64-95 2L^2-I, 96-127 4L^3-3L.
    // B-fragments of M^T: MGf[jt][lane][j] = M[col=jt*16+(lane&15)][k=(lane>>4)*8+j]
    u16* MGf = (u16*)(ws + WS_MGF);
    for (int i = tid; i < 4096; i += 256) {
      int jt = i >> 9, lane = (i >> 3) & 63, j = i & 7;
      int col = jt * 16 + (lane & 15);
      int k = ((lane >> 4) << 3) + j;
      int kk = col >> 5, np = col & 31;
      float v;
      if (kk == 0)      v = (np == k) ? 1.0f : 0.0f;
      else if (kk == 1) v = Ls[np * 32 + k];
      else if (kk == 2) v = 2.0f * L2s[np * 32 + k] - (np == k ? 1.0f : 0.0f);
      else              v = 4.0f * L3s[np * 32 + k] - 3.0f * Ls[np * 32 + k];
      MGf[i] = f2bf(v);
    }
    float* B1 = (float*)(ws + WS_B1);
    float* B2 = (float*)(ws + WS_B2);
    if (tid < 128) {
      float s = b1[tid];
      for (int c = 0; c < 60; ++c) s += w1[(c * 5) * 128 + tid];
      B1[tid] = s;
    } else {
      int o = tid - 128;
      float s = b2[o];
      for (int c = 0; c < 128; ++c) s += w2[(c * 5) * 128 + o];
      B2[o] = s;
    }
  } else {
    u16* WT1F = (u16*)(ws + WS_WT1F);
    u16* WT2F = (u16*)(ws + WS_WT2F);
    int g = (blockIdx.x - 1) * 256 + tid;
    // WT1F bits: j[0:3) lane[3:9) ks[9:11) h[11:12) ot[12:15)
    // element = w1 at kterm=ks, c = h*32 + (j>>2)*16 + q*4 + (j&3) (0 if c>=60),
    // o = ot*16+(lane&15)   [kc-permuted order]
    for (int i = g; i < 32768; i += 16 * 256) {
      int j = i & 7, lane = (i >> 3) & 63, ks = (i >> 9) & 3;
      int h = (i >> 11) & 1, ot = i >> 12;
      int q = lane >> 4;
      int c = h * 32 + ((j >> 2) << 4) + q * 4 + (j & 3);
      int o = ot * 16 + (lane & 15);
      WT1F[i] = (c < 60) ? f2bf(w1[(c * 5 + ks + 1) * 128 + o]) : (u16)0;
    }
    // WT2F bits: j[0:3) lane[3:9) ks[9:11) h[11:13) mt[13:16)
    // element = w2 at kterm=ks, c2 = h*32 + (j>>2)*16 + q*4 + (j&3),
    // o = mt*16+(lane&15)   [kc-permuted order]
    for (int i = g; i < 65536; i += 16 * 256) {
      int j = i & 7, lane = (i >> 3) & 63, ks = (i >> 9) & 3;
      int h = (i >> 11) & 3, mt = i >> 13;
      int q = lane >> 4;
      int c2 = h * 32 + ((j >> 2) << 4) + q * 4 + (j & 3);
      int o = mt * 16 + (lane & 15);
      WT2F[i] = f2bf(w2[(c2 * 5 + ks + 1) * 128 + o]);
    }
  }
}

// 2 batches per block, 4 waves; wave role = (batch = w>>1, o-half = w&1).
// Each wave is BATCH-PRIVATE: reads only its batch's Xt/Y/Ht (halves the
// block's Y-read ds-pipe traffic, the dominant LDS consumer), produces the
// Y slices for kterms {2*oh, 2*oh+1} of its batch, and owns o = oh*64..+63
// (4 o-tiles) in both einsums. Weight-frag registers are no longer shared
// across batches (2x L2 traffic, ~21 TB/s aggregate -- under the ceiling).
// LDS layouts (32768 B, 4 blocks/CU):
//   Xt [64 c][40] u16       pad-stride, 5120 B/batch
//   Ht [128 o][32] u16      slot swizzle ps = s ^ (l15&3) ^ (l15>>2); 8 KB/batch
//   Y  [32 np][128 kc] u16  16B-slot swizzle ps = s ^ (np&7); 8 KB/batch
//   Ht overlays Xt; red overlays Ht in the epilogue.
__global__ __launch_bounds__(256, 4) void dgcnn_kernel(
    const float* __restrict__ x,
    const char* __restrict__ ws,
    const float* __restrict__ fc_w,
    const float* __restrict__ fc_b,
    float* __restrict__ out) {
  __shared__ __align__(16) char arena[32768];
  u16* XtA = (u16*)arena;             // 5120 B
  u16* XtB = (u16*)(arena + 5120);    // 5120 B
  u16* HtA = (u16*)arena;             // 8192 B (after Xt dead)
  u16* HtB = (u16*)(arena + 8192);    // 8192 B
  u16* YA  = (u16*)(arena + 16384);   // 8192 B
  u16* YB  = (u16*)(arena + 24576);   // 8192 B
  float* red = (float*)arena;         // epilogue overlay (Ht dead)

  const u16* MGf  = (const u16*)(ws + WS_MGF);
  const u16* WT1F = (const u16*)(ws + WS_WT1F);
  const u16* WT2F = (const u16*)(ws + WS_WT2F);
  const float* bias1 = (const float*)(ws + WS_B1);
  const float* bias2 = (const float*)(ws + WS_B2);

  const int tid = threadIdx.x;
  const int w = tid >> 6, lane = tid & 63;
  const int l15 = lane & 15, q = lane >> 4;
  const int bw = w >> 1;   // batch within the pair
  const int oh = w & 1;    // o-half AND kterm-pair index
  const int b0 = blockIdx.x * 2;
  const f32x4 z4 = {0.0f, 0.0f, 0.0f, 0.0f};

  u16* Xt = bw ? XtB : XtA;
  u16* Ht = bw ? HtB : HtA;
  u16* Y  = bw ? YB  : YA;

  // M^T B-fragments: this wave produces kterms kt = oh*2+ktl, col tiles ct.
  bf16x8 mB[2][2];
#pragma unroll
  for (int ktl = 0; ktl < 2; ++ktl)
#pragma unroll
    for (int ct = 0; ct < 2; ++ct)
      mB[ktl][ct] = *(const bf16x8*)(MGf + (((oh * 2 + ktl) * 2 + ct) * 64 + lane) * 8);

  // ---- stage x^T (both batches, all 256 threads), coalesced float4 loads.
  const float* xb = x + (size_t)b0 * 1920;
  {
    int tn = (tid & 15) * 2;   // node pair n, n+1
    int tc = (tid >> 4) * 4;   // channel quad c..c+3
    if (tc < 60) {
      float4 a0 = *(const float4*)(xb + tn * 60 + tc);
      float4 a1 = *(const float4*)(xb + tn * 60 + 60 + tc);
      float4 c0 = *(const float4*)(xb + 1920 + tn * 60 + tc);
      float4 c1 = *(const float4*)(xb + 1920 + tn * 60 + 60 + tc);
      *(u32*)&XtA[(tc + 0) * 40 + tn] = pk2bf(a0.x, a1.x);
      *(u32*)&XtA[(tc + 1) * 40 + tn] = pk2bf(a0.y, a1.y);
      *(u32*)&XtA[(tc + 2) * 40 + tn] = pk2bf(a0.z, a1.z);
      *(u32*)&XtA[(tc + 3) * 40 + tn] = pk2bf(a0.w, a1.w);
      *(u32*)&XtB[(tc + 0) * 40 + tn] = pk2bf(c0.x, c1.x);
      *(u32*)&XtB[(tc + 1) * 40 + tn] = pk2bf(c0.y, c1.y);
      *(u32*)&XtB[(tc + 2) * 40 + tn] = pk2bf(c0.z, c1.z);
      *(u32*)&XtB[(tc + 3) * 40 + tn] = pk2bf(c0.w, c1.w);
    } else {
#pragma unroll
      for (int j = 0; j < 4; ++j) {
        *(u32*)&XtA[(tc + j) * 40 + tn] = 0;
        *(u32*)&XtB[(tc + j) * 40 + tn] = 0;
      }
    }
  }
  __syncthreads();

  // Y write slots for this wave's two kterms (16B slot, XOR np&7 swizzle).
  const int yswk0 = (((oh * 2 + 0) * 4 + q) ^ (l15 & 7)) * 8;  // u16 units
  const int yswk1 = (((oh * 2 + 1) * 4 + q) ^ (l15 & 7)) * 8;

  // G1 node-mix + pack + Y write, shared by both layers (a0/a1 = A-frags).
#define G1_EMIT(a0_, a1_)                                                    \
  {                                                                          \
    f32x4 g00 = MFMA16(a0_, mB[0][0], z4), g01 = MFMA16(a0_, mB[0][1], z4);  \
    f32x4 g10 = MFMA16(a0_, mB[1][0], z4), g11 = MFMA16(a0_, mB[1][1], z4);  \
    f32x4 h00 = MFMA16(a1_, mB[0][0], z4), h01 = MFMA16(a1_, mB[0][1], z4);  \
    f32x4 h10 = MFMA16(a1_, mB[1][0], z4), h11 = MFMA16(a1_, mB[1][1], z4);  \
    u32x4 v;                                                                 \
    v = (u32x4){pk2bf(g00[0], g00[1]), pk2bf(g00[2], g00[3]),                \
                pk2bf(h00[0], h00[1]), pk2bf(h00[2], h00[3])};               \
    *(u32x4*)&Y[(0 * 16 + l15) * 128 + yswk0] = v;                           \
    v = (u32x4){pk2bf(g01[0], g01[1]), pk2bf(g01[2], g01[3]),                \
                pk2bf(h01[0], h01[1]), pk2bf(h01[2], h01[3])};               \
    *(u32x4*)&Y[(1 * 16 + l15) * 128 + yswk0] = v;                           \
    v = (u32x4){pk2bf(g10[0], g10[1]), pk2bf(g10[2], g10[3]),                \
                pk2bf(h10[0], h10[1]), pk2bf(h10[2], h10[3])};               \
    *(u32x4*)&Y[(0 * 16 + l15) * 128 + yswk1] = v;                           \
    v = (u32x4){pk2bf(g11[0], g11[1]), pk2bf(g11[2], g11[3]),                \
                pk2bf(h11[0], h11[1]), pk2bf(h11[2], h11[3])};               \
    *(u32x4*)&Y[(1 * 16 + l15) * 128 + yswk1] = v;                           \
  }
  // NOTE: g{mtl}{ct} packing into slot elems: j>>2 = mtl, j&3 = reg, matching
  // the kc-permutation c_local = (j>>2)*16 + q*4 + (j&3).

  // ---------------- layer 1: 2 kc-chunks, acc carried in regs ----------------
  f32x4 acc1[2][4];  // [nt][otl], o = (oh*4+otl)*16+..
#pragma unroll
  for (int nt = 0; nt < 2; ++nt)
#pragma unroll
    for (int otl = 0; otl < 4; ++otl) acc1[nt][otl] = z4;

#pragma unroll
  for (int h = 0; h < 2; ++h) {
    {
      int r0 = ((2 * h + 0) * 16 + l15) * 40 + q * 8;
      int r1 = ((2 * h + 1) * 16 + l15) * 40 + q * 8;
      bf16x8 a0 = *(const bf16x8*)&Xt[r0];
      bf16x8 a1 = *(const bf16x8*)&Xt[r1];
      G1_EMIT(a0, a1);
    }
    __syncthreads();
    // einsum1 partial over this chunk's 128 kc (full kc, own batch, 4 o-tiles)
#pragma unroll
    for (int ks = 0; ks < 4; ++ks) {
      const u16* wp = WT1F + (size_t)((((oh * 4) * 2 + h) * 4 + ks) * 64 + lane) * 8;
      bf16x8 wf0 = *(const bf16x8*)wp;
      bf16x8 wf1 = *(const bf16x8*)(wp + 4096);
      bf16x8 wf2 = *(const bf16x8*)(wp + 8192);
      bf16x8 wf3 = *(const bf16x8*)(wp + 12288);
      int ysw = ((ks * 4 + q) ^ (l15 & 7)) * 8;
      bf16x8 a0 = *(const bf16x8*)&Y[l15 * 128 + ysw];
      bf16x8 a1 = *(const bf16x8*)&Y[(16 + l15) * 128 + ysw];
      acc1[0][0] = MFMA16(a0, wf0, acc1[0][0]);
      acc1[0][1] = MFMA16(a0, wf1, acc1[0][1]);
      acc1[0][2] = MFMA16(a0, wf2, acc1[0][2]);
      acc1[0][3] = MFMA16(a0, wf3, acc1[0][3]);
      acc1[1][0] = MFMA16(a1, wf0, acc1[1][0]);
      acc1[1][1] = MFMA16(a1, wf1, acc1[1][1]);
      acc1[1][2] = MFMA16(a1, wf2, acc1[1][2]);
      acc1[1][3] = MFMA16(a1, wf3, acc1[1][3]);
    }
    if (h == 0) __syncthreads();  // next G1 rewrites Y
  }
  // bias+relu -> Ht (own batch, own o-half; Xt dead past this barrier)
#pragma unroll
  for (int otl = 0; otl < 4; ++otl) {
    int o = (oh * 4 + otl) * 16 + l15;
    float bv = bias1[o];
#pragma unroll
    for (int nt = 0; nt < 2; ++nt) {
      int ps = (nt * 2 + (q >> 1)) ^ (l15 & 3) ^ (l15 >> 2);
      int idx = o * 32 + ps * 8 + (q & 1) * 4;
      uint2 v;
      v.x = pk2bf(fmaxf(acc1[nt][otl][0] + bv, 0.0f), fmaxf(acc1[nt][otl][1] + bv, 0.0f));
      v.y = pk2bf(fmaxf(acc1[nt][otl][2] + bv, 0.0f), fmaxf(acc1[nt][otl][3] + bv, 0.0f));
      *(uint2*)&Ht[idx] = v;
    }
  }
  __syncthreads();

  // ---------------- layer 2: 4 kc-chunks, acc carried in regs ----------------
  f32x4 acc2[4][2];  // [otl][nt]
#pragma unroll
  for (int otl = 0; otl < 4; ++otl)
#pragma unroll
    for (int nt = 0; nt < 2; ++nt) acc2[otl][nt] = z4;

#pragma unroll
  for (int h = 0; h < 4; ++h) {
    {
      int psr = (q ^ (l15 & 3) ^ (l15 >> 2)) * 8;
      int o20 = ((2 * h + 0) * 16 + l15) * 32;
      int o21 = ((2 * h + 1) * 16 + l15) * 32;
      bf16x8 a0 = *(const bf16x8*)&Ht[o20 + psr];
      bf16x8 a1 = *(const bf16x8*)&Ht[o21 + psr];
      G1_EMIT(a0, a1);
    }
    __syncthreads();
    // einsum2 (flipped): D[o][n] += Wp2^T[o][chunk kc] @ Y^T[kc][n]
#pragma unroll
    for (int ks = 0; ks < 4; ++ks) {
      const u16* wp = WT2F + (size_t)((((oh * 4) * 4 + h) * 4 + ks) * 64 + lane) * 8;
      bf16x8 wf0 = *(const bf16x8*)wp;
      bf16x8 wf1 = *(const bf16x8*)(wp + 8192);
      bf16x8 wf2 = *(const bf16x8*)(wp + 16384);
      bf16x8 wf3 = *(const bf16x8*)(wp + 24576);
      int ysw = ((ks * 4 + q) ^ (l15 & 7)) * 8;
      bf16x8 by0 = *(const bf16x8*)&Y[l15 * 128 + ysw];
      bf16x8 by1 = *(const bf16x8*)&Y[(16 + l15) * 128 + ysw];
      acc2[0][0] = MFMA16(wf0, by0, acc2[0][0]);
      acc2[0][1] = MFMA16(wf0, by1, acc2[0][1]);
      acc2[1][0] = MFMA16(wf1, by0, acc2[1][0]);
      acc2[1][1] = MFMA16(wf1, by1, acc2[1][1]);
      acc2[2][0] = MFMA16(wf2, by0, acc2[2][0]);
      acc2[2][1] = MFMA16(wf2, by1, acc2[2][1]);
      acc2[3][0] = MFMA16(wf3, by0, acc2[3][0]);
      acc2[3][1] = MFMA16(wf3, by1, acc2[3][1]);
    }
    if (h < 3) __syncthreads();  // next G1 rewrites Y
  }

  // ---- epilogue: bias2+relu in regs, fc directly from accumulators ----
  float p0 = 0.0f, p1 = 0.0f;
#pragma unroll
  for (int otl = 0; otl < 4; ++otl) {
    int ob = (oh * 4 + otl) * 16 + q * 4;  // o base, 4 contiguous per lane
    float4 bv = *(const float4*)&bias2[ob];
#pragma unroll
    for (int nt = 0; nt < 2; ++nt) {
      int n = nt * 16 + l15;
      float4 w0 = *(const float4*)&fc_w[n * 128 + ob];
      float4 w1v = *(const float4*)&fc_w[4096 + n * 128 + ob];
      float h0 = fmaxf(acc2[otl][nt][0] + bv.x, 0.0f);
      float h1 = fmaxf(acc2[otl][nt][1] + bv.y, 0.0f);
      float h2 = fmaxf(acc2[otl][nt][2] + bv.z, 0.0f);
      float h3 = fmaxf(acc2[otl][nt][3] + bv.w, 0.0f);
      p0 = fmaf(h0, w0.x, fmaf(h1, w0.y, fmaf(h2, w0.z, fmaf(h3, w0.w, p0))));
      p1 = fmaf(h0, w1v.x, fmaf(h1, w1v.y, fmaf(h2, w1v.z, fmaf(h3, w1v.w, p1))));
    }
  }
#pragma unroll
  for (int off = 32; off >= 1; off >>= 1) {
    p0 += __shfl_xor(p0, off);
    p1 += __shfl_xor(p1, off);
  }
  if (lane == 0) {
    red[w * 2 + 0] = p0;
    red[w * 2 + 1] = p1;
  }
  __syncthreads();
  if (tid < 4) {
    int bt = tid >> 1, j = tid & 1;
    float s = red[bt * 4 + j] + red[bt * 4 + 2 + j] + fc_b[j];
    out[(size_t)(b0 + bt) * 2 + j] = s;
  }
}

extern "C" void kernel_launch(void* const* d_in, const int* in_sizes, int n_in,
                              void* d_out, int out_size, void* d_ws, size_t ws_size,
                              hipStream_t stream) {
  const float* x        = (const float*)d_in[0];
  const float* adj      = (const float*)d_in[1];
  const float* adj_bias = (const float*)d_in[2];
  const float* w1       = (const float*)d_in[3];
  const float* b1       = (const float*)d_in[4];
  const float* w2       = (const float*)d_in[5];
  const float* b2       = (const float*)d_in[6];
  const float* fc_w     = (const float*)d_in[7];
  const float* fc_b     = (const float*)d_in[8];
  float* out = (float*)d_out;
  char* ws   = (char*)d_ws;

  prep_kernel<<<17, 256, 0, stream>>>(adj, adj_bias, w1, b1, w2, b2, ws);
  dgcnn_kernel<<<4096, 256, 0, stream>>>(x, ws, fc_w, fc_b, out);
}

// Round 5
// 178.508 us; speedup vs baseline: 1.1513x; 1.1513x over previous
//
#include <hip/hip_runtime.h>

typedef unsigned short u16;
typedef unsigned int u32;
typedef short bf16x8 __attribute__((ext_vector_type(8)));
typedef float f32x4 __attribute__((ext_vector_type(4)));
typedef u32 u32x4 __attribute__((ext_vector_type(4)));

#define MFMA16(a, b, c) __builtin_amdgcn_mfma_f32_16x16x32_bf16((a), (b), (c), 0, 0, 0)

__device__ __forceinline__ u16 f2bf(float f) {
  u32 u = __builtin_bit_cast(u32, f);
  u += 0x7FFFu + ((u >> 16) & 1u);
  return (u16)(u >> 16);
}
// packed f32x2 -> bf16x2, software RNE. NOTE (R4 post-mortem): inline-asm
// v_cvt_pk_bf16_f32 produced NaN on this toolchain -- do NOT reintroduce it.
__device__ __forceinline__ u32 pk2bf(float a, float b) {
  return (u32)f2bf(a) | ((u32)f2bf(b) << 16);
}

// ws byte offsets
#define WS_MGF   0         // bf16 [8 jt][64 lane][8 j]      B-frags of M^T   (8192 B)
#define WS_WT1F  8192      // bf16 [8 ot][2 h][4 ks][64][8]  B-frags of Wp1   (65536 B)
#define WS_WT2F  73728     // bf16 [8 mt][4 h][4 ks][64][8]  A-frags of Wp2^T (131072 B)
#define WS_B1    204800    // f32 [128]  bias1 + T0-fold
#define WS_B2    205312    // f32 [128]  bias2 + T0-fold

// NOTE on element order (kc-permutation): within each 32-wide kc chunk, the
// fragment element at (reader lane q, elem j) holds channel
//   c_local = (j>>2)*16 + q*4 + (j&3)
// chosen so the G1 producer's 8 outputs per lane are CONTIGUOUS in LDS
// (one ds_write_b128). WT1F/WT2F below are built with the same order.
__global__ void prep_kernel(const float* __restrict__ adj,
                            const float* __restrict__ adj_bias,
                            const float* __restrict__ w1,
                            const float* __restrict__ b1,
                            const float* __restrict__ w2,
                            const float* __restrict__ b2,
                            char* __restrict__ ws) {
  const int tid = threadIdx.x;
  if (blockIdx.x == 0) {
    __shared__ float sa[1024], Ls[1024], L2s[1024], L3s[1024], sdre[32];
    float bias = adj_bias[0];
    for (int i = tid; i < 1024; i += 256) sa[i] = fmaxf(adj[i] + bias, 0.0f);
    __syncthreads();
    if (tid < 32) {
      float s = 0.0f;
      for (int c = 0; c < 32; ++c) s += sa[tid * 32 + c];
      sdre[tid] = 1.0f / sqrtf(s + 1e-5f);
    }
    __syncthreads();
    for (int i = tid; i < 1024; i += 256) {
      int n = i >> 5, c = i & 31;
      Ls[i] = (n == c ? 1.0f : 0.0f) - sdre[n] * sa[i] * sdre[c];
    }
    __syncthreads();
    for (int i = tid; i < 1024; i += 256) {
      int r = i >> 5, c = i & 31;
      float s = 0.0f;
      for (int m = 0; m < 32; ++m) s += Ls[r * 32 + m] * Ls[m * 32 + c];
      L2s[i] = s;
    }
    __syncthreads();
    for (int i = tid; i < 1024; i += 256) {
      int r = i >> 5, c = i & 31;
      float s = 0.0f;
      for (int m = 0; m < 32; ++m) s += L2s[r * 32 + m] * Ls[m * 32 + c];
      L3s[i] = s;
    }
    __syncthreads();
    // M stacked [128x32]: rows 0-31 I, 32-63 L, 64-95 2L^2-I, 96-127 4L^3-3L.
    // B-fragments of M^T: MGf[jt][lane][j] = M[col=jt*16+(lane&15)][k=(lane>>4)*8+j]
    u16* MGf = (u16*)(ws + WS_MGF);
    for (int i = tid; i < 4096; i += 256) {
      int jt = i >> 9, lane = (i >> 3) & 63, j = i & 7;
      int col = jt * 16 + (lane & 15);
      int k = ((lane >> 4) << 3) + j;
      int kk = col >> 5, np = col & 31;
      float v;
      if (kk == 0)      v = (np == k) ? 1.0f : 0.0f;
      else if (kk == 1) v = Ls[np * 32 + k];
      else if (kk == 2) v = 2.0f * L2s[np * 32 + k] - (np == k ? 1.0f : 0.0f);
      else              v = 4.0f * L3s[np * 32 + k] - 3.0f * Ls[np * 32 + k];
      MGf[i] = f2bf(v);
    }
    float* B1 = (float*)(ws + WS_B1);
    float* B2 = (float*)(ws + WS_B2);
    if (tid < 128) {
      float s = b1[tid];
      for (int c = 0; c < 60; ++c) s += w1[(c * 5) * 128 + tid];
      B1[tid] = s;
    } else {
      int o = tid - 128;
      float s = b2[o];
      for (int c = 0; c < 128; ++c) s += w2[(c * 5) * 128 + o];
      B2[o] = s;
    }
  } else {
    u16* WT1F = (u16*)(ws + WS_WT1F);
    u16* WT2F = (u16*)(ws + WS_WT2F);
    int g = (blockIdx.x - 1) * 256 + tid;
    // WT1F bits: j[0:3) lane[3:9) ks[9:11) h[11:12) ot[12:15)
    // element = w1 at kterm=ks, c = h*32 + (j>>2)*16 + q*4 + (j&3) (0 if c>=60),
    // o = ot*16+(lane&15)   [kc-permuted order]
    for (int i = g; i < 32768; i += 16 * 256) {
      int j = i & 7, lane = (i >> 3) & 63, ks = (i >> 9) & 3;
      int h = (i >> 11) & 1, ot = i >> 12;
      int q = lane >> 4;
      int c = h * 32 + ((j >> 2) << 4) + q * 4 + (j & 3);
      int o = ot * 16 + (lane & 15);
      WT1F[i] = (c < 60) ? f2bf(w1[(c * 5 + ks + 1) * 128 + o]) : (u16)0;
    }
    // WT2F bits: j[0:3) lane[3:9) ks[9:11) h[11:13) mt[13:16)
    // element = w2 at kterm=ks, c2 = h*32 + (j>>2)*16 + q*4 + (j&3),
    // o = mt*16+(lane&15)   [kc-permuted order]
    for (int i = g; i < 65536; i += 16 * 256) {
      int j = i & 7, lane = (i >> 3) & 63, ks = (i >> 9) & 3;
      int h = (i >> 11) & 3, mt = i >> 13;
      int q = lane >> 4;
      int c2 = h * 32 + ((j >> 2) << 4) + q * 4 + (j & 3);
      int o = mt * 16 + (lane & 15);
      WT2F[i] = f2bf(w2[(c2 * 5 + ks + 1) * 128 + o]);
    }
  }
}

// R1-proven structure: 2 batches per block, each wave handles BOTH batches
// (shared weight frags, batch-level ILP in the MFMA chains).
// LDS layouts (32768 B, 4 blocks/CU, launch_bounds(256,4) -> no spill):
//   Xt [64 c][40] u16       pad-stride (reads conflict-free), 5120 B/batch
//   Ht [128 o][32] u16      slot swizzle ps = s ^ (l15&3) ^ (l15>>2)
//                           (full-rank: kills the 2-way read conflict)
//   Y  [32 np][128 kc] u16  16B-slot swizzle ps = s ^ (np&7); 8 KB/batch
//   Ht overlays Xt (Xt dead after layer-1 G1); red overlays Ht in epilogue.
__global__ __launch_bounds__(256, 4) void dgcnn_kernel(
    const float* __restrict__ x,
    const char* __restrict__ ws,
    const float* __restrict__ fc_w,
    const float* __restrict__ fc_b,
    float* __restrict__ out) {
  __shared__ __align__(16) char arena[32768];
  u16* XtA = (u16*)arena;             // 5120 B
  u16* XtB = (u16*)(arena + 5120);    // 5120 B
  u16* HtA = (u16*)arena;             // 8192 B (after Xt dead)
  u16* HtB = (u16*)(arena + 8192);    // 8192 B
  u16* YA  = (u16*)(arena + 16384);   // 8192 B
  u16* YB  = (u16*)(arena + 24576);   // 8192 B
  float* red = (float*)arena;         // epilogue overlay (Ht dead)

  const u16* MGf  = (const u16*)(ws + WS_MGF);
  const u16* WT1F = (const u16*)(ws + WS_WT1F);
  const u16* WT2F = (const u16*)(ws + WS_WT2F);
  const float* bias1 = (const float*)(ws + WS_B1);
  const float* bias2 = (const float*)(ws + WS_B2);

  const int tid = threadIdx.x;
  const int w = tid >> 6, lane = tid & 63;
  const int l15 = lane & 15, q = lane >> 4;
  const int b0 = blockIdx.x * 2;
  const f32x4 z4 = {0.0f, 0.0f, 0.0f, 0.0f};

  // M^T B-fragments: wave w covers M^T col tiles 2w, 2w+1 (k-term = w)
  bf16x8 mB0 = *(const bf16x8*)(MGf + ((2 * w + 0) * 64 + lane) * 8);
  bf16x8 mB1 = *(const bf16x8*)(MGf + ((2 * w + 1) * 64 + lane) * 8);

  // ---- stage x^T (both batches), coalesced float4 loads, b32 node-pair
  // writes (2-way banks = free). Threads with tc==60 write the zero rows.
  const float* xb = x + (size_t)b0 * 1920;
  {
    int tn = (tid & 15) * 2;   // node pair n, n+1
    int tc = (tid >> 4) * 4;   // channel quad c..c+3
    if (tc < 60) {
      float4 a0 = *(const float4*)(xb + tn * 60 + tc);
      float4 a1 = *(const float4*)(xb + tn * 60 + 60 + tc);
      float4 c0 = *(const float4*)(xb + 1920 + tn * 60 + tc);
      float4 c1 = *(const float4*)(xb + 1920 + tn * 60 + 60 + tc);
      *(u32*)&XtA[(tc + 0) * 40 + tn] = pk2bf(a0.x, a1.x);
      *(u32*)&XtA[(tc + 1) * 40 + tn] = pk2bf(a0.y, a1.y);
      *(u32*)&XtA[(tc + 2) * 40 + tn] = pk2bf(a0.z, a1.z);
      *(u32*)&XtA[(tc + 3) * 40 + tn] = pk2bf(a0.w, a1.w);
      *(u32*)&XtB[(tc + 0) * 40 + tn] = pk2bf(c0.x, c1.x);
      *(u32*)&XtB[(tc + 1) * 40 + tn] = pk2bf(c0.y, c1.y);
      *(u32*)&XtB[(tc + 2) * 40 + tn] = pk2bf(c0.z, c1.z);
      *(u32*)&XtB[(tc + 3) * 40 + tn] = pk2bf(c0.w, c1.w);
    } else {
#pragma unroll
      for (int j = 0; j < 4; ++j) {
        *(u32*)&XtA[(tc + j) * 40 + tn] = 0;
        *(u32*)&XtB[(tc + j) * 40 + tn] = 0;
      }
    }
  }
  __syncthreads();

  // G1 write swizzle: 16B slot (w*4+q) XOR'd with (np&7); same for both jtl.
  const int ysw_w = ((w * 4 + q) ^ (l15 & 7)) * 8;  // u16 units

  // ---------------- layer 1: 2 kc-chunks, acc carried in regs ----------------
  f32x4 acc1A[2][2] = {{z4, z4}, {z4, z4}};  // [nt][ot]
  f32x4 acc1B[2][2] = {{z4, z4}, {z4, z4}};
#pragma unroll
  for (int h = 0; h < 2; ++h) {
    // G1: Y[np][kc-perm] = T~[kterm=w][np][c = 32h + c_local]
    {
      f32x4 gA[2][2], gB[2][2];
#pragma unroll
      for (int mtl = 0; mtl < 2; ++mtl) {
        int roff = ((2 * h + mtl) * 16 + l15) * 40 + q * 8;
        bf16x8 aA = *(const bf16x8*)&XtA[roff];
        bf16x8 aB = *(const bf16x8*)&XtB[roff];
        gA[mtl][0] = MFMA16(aA, mB0, z4);
        gA[mtl][1] = MFMA16(aA, mB1, z4);
        gB[mtl][0] = MFMA16(aB, mB0, z4);
        gB[mtl][1] = MFMA16(aB, mB1, z4);
      }
#pragma unroll
      for (int jtl = 0; jtl < 2; ++jtl) {
        int yoff = (jtl * 16 + l15) * 128 + ysw_w;
        u32x4 vA = {pk2bf(gA[0][jtl][0], gA[0][jtl][1]),
                    pk2bf(gA[0][jtl][2], gA[0][jtl][3]),
                    pk2bf(gA[1][jtl][0], gA[1][jtl][1]),
                    pk2bf(gA[1][jtl][2], gA[1][jtl][3])};
        u32x4 vB = {pk2bf(gB[0][jtl][0], gB[0][jtl][1]),
                    pk2bf(gB[0][jtl][2], gB[0][jtl][3]),
                    pk2bf(gB[1][jtl][0], gB[1][jtl][1]),
                    pk2bf(gB[1][jtl][2], gB[1][jtl][3])};
        *(u32x4*)&YA[yoff] = vA;
        *(u32x4*)&YB[yoff] = vB;
      }
    }
    __syncthreads();
    // einsum1 partial over this chunk's 128 kc
#pragma unroll
    for (int ks = 0; ks < 4; ++ks) {
      const u16* wp = WT1F + (size_t)((((2 * w) * 2 + h) * 4 + ks) * 64 + lane) * 8;
      bf16x8 wfa = *(const bf16x8*)wp;
      bf16x8 wfb = *(const bf16x8*)(wp + 4096);  // ot+1
      int ysw = ((ks * 4 + q) ^ (l15 & 7)) * 8;
      bf16x8 a0A = *(const bf16x8*)&YA[l15 * 128 + ysw];
      bf16x8 a1A = *(const bf16x8*)&YA[(16 + l15) * 128 + ysw];
      bf16x8 a0B = *(const bf16x8*)&YB[l15 * 128 + ysw];
      bf16x8 a1B = *(const bf16x8*)&YB[(16 + l15) * 128 + ysw];
      acc1A[0][0] = MFMA16(a0A, wfa, acc1A[0][0]);
      acc1A[0][1] = MFMA16(a0A, wfb, acc1A[0][1]);
      acc1A[1][0] = MFMA16(a1A, wfa, acc1A[1][0]);
      acc1A[1][1] = MFMA16(a1A, wfb, acc1A[1][1]);
      acc1B[0][0] = MFMA16(a0B, wfa, acc1B[0][0]);
      acc1B[0][1] = MFMA16(a0B, wfb, acc1B[0][1]);
      acc1B[1][0] = MFMA16(a1B, wfa, acc1B[1][0]);
      acc1B[1][1] = MFMA16(a1B, wfb, acc1B[1][1]);
    }
    if (h == 0) __syncthreads();  // next G1 rewrites Y
  }
  // bias+relu -> Ht (Xt dead: all Xt reads preceded the last post-G1 barrier)
#pragma unroll
  for (int ot = 0; ot < 2; ++ot) {
    int o = (2 * w + ot) * 16 + l15;
    float bv = bias1[o];
#pragma unroll
    for (int mt = 0; mt < 2; ++mt) {
      // logical n-slot s = mt*2 + (q>>1); physical = s ^ (l15&3) ^ (l15>>2)
      int ps = (mt * 2 + (q >> 1)) ^ (l15 & 3) ^ (l15 >> 2);
      int idx = o * 32 + ps * 8 + (q & 1) * 4;
      uint2 vA, vB;
      vA.x = pk2bf(fmaxf(acc1A[mt][ot][0] + bv, 0.0f), fmaxf(acc1A[mt][ot][1] + bv, 0.0f));
      vA.y = pk2bf(fmaxf(acc1A[mt][ot][2] + bv, 0.0f), fmaxf(acc1A[mt][ot][3] + bv, 0.0f));
      vB.x = pk2bf(fmaxf(acc1B[mt][ot][0] + bv, 0.0f), fmaxf(acc1B[mt][ot][1] + bv, 0.0f));
      vB.y = pk2bf(fmaxf(acc1B[mt][ot][2] + bv, 0.0f), fmaxf(acc1B[mt][ot][3] + bv, 0.0f));
      *(uint2*)&HtA[idx] = vA;
      *(uint2*)&HtB[idx] = vB;
    }
  }
  __syncthreads();

  // ---------------- layer 2: 4 kc-chunks, acc carried in regs ----------------
  f32x4 acc2A[2][2] = {{z4, z4}, {z4, z4}};  // [ot][nt]
  f32x4 acc2B[2][2] = {{z4, z4}, {z4, z4}};
#pragma unroll
  for (int h = 0; h < 4; ++h) {
    // G1: Y[np][kc-perm] = T~2[kterm=w][np][o = 32h + c2_local]
    {
      f32x4 gA[2][2], gB[2][2];
#pragma unroll
      for (int mtl = 0; mtl < 2; ++mtl) {
        int o2 = (2 * h + mtl) * 16 + l15;
        int ps = q ^ (l15 & 3) ^ (l15 >> 2);
        bf16x8 aA = *(const bf16x8*)&HtA[o2 * 32 + ps * 8];
        bf16x8 aB = *(const bf16x8*)&HtB[o2 * 32 + ps * 8];
        gA[mtl][0] = MFMA16(aA, mB0, z4);
        gA[mtl][1] = MFMA16(aA, mB1, z4);
        gB[mtl][0] = MFMA16(aB, mB0, z4);
        gB[mtl][1] = MFMA16(aB, mB1, z4);
      }
#pragma unroll
      for (int jtl = 0; jtl < 2; ++jtl) {
        int yoff = (jtl * 16 + l15) * 128 + ysw_w;
        u32x4 vA = {pk2bf(gA[0][jtl][0], gA[0][jtl][1]),
                    pk2bf(gA[0][jtl][2], gA[0][jtl][3]),
                    pk2bf(gA[1][jtl][0], gA[1][jtl][1]),
                    pk2bf(gA[1][jtl][2], gA[1][jtl][3])};
        u32x4 vB = {pk2bf(gB[0][jtl][0], gB[0][jtl][1]),
                    pk2bf(gB[0][jtl][2], gB[0][jtl][3]),
                    pk2bf(gB[1][jtl][0], gB[1][jtl][1]),
                    pk2bf(gB[1][jtl][2], gB[1][jtl][3])};
        *(u32x4*)&YA[yoff] = vA;
        *(u32x4*)&YB[yoff] = vB;
      }
    }
    __syncthreads();
    // einsum2 partial (flipped): D[o][n] += Wp2^T[o][chunk kc] @ Y^T[kc][n]
#pragma unroll
    for (int ks = 0; ks < 4; ++ks) {
      const u16* wp = WT2F + (size_t)((((2 * w) * 4 + h) * 4 + ks) * 64 + lane) * 8;
      bf16x8 wfa = *(const bf16x8*)wp;
      bf16x8 wfb = *(const bf16x8*)(wp + 8192);  // mt+1
      int ysw = ((ks * 4 + q) ^ (l15 & 7)) * 8;
      bf16x8 by0A = *(const bf16x8*)&YA[l15 * 128 + ysw];
      bf16x8 by1A = *(const bf16x8*)&YA[(16 + l15) * 128 + ysw];
      bf16x8 by0B = *(const bf16x8*)&YB[l15 * 128 + ysw];
      bf16x8 by1B = *(const bf16x8*)&YB[(16 + l15) * 128 + ysw];
      acc2A[0][0] = MFMA16(wfa, by0A, acc2A[0][0]);
      acc2A[0][1] = MFMA16(wfa, by1A, acc2A[0][1]);
      acc2A[1][0] = MFMA16(wfb, by0A, acc2A[1][0]);
      acc2A[1][1] = MFMA16(wfb, by1A, acc2A[1][1]);
      acc2B[0][0] = MFMA16(wfa, by0B, acc2B[0][0]);
      acc2B[0][1] = MFMA16(wfa, by1B, acc2B[0][1]);
      acc2B[1][0] = MFMA16(wfb, by0B, acc2B[1][0]);
      acc2B[1][1] = MFMA16(wfb, by1B, acc2B[1][1]);
    }
    if (h < 3) __syncthreads();  // next G1 rewrites Y
  }

  // ---- epilogue: bias2+relu in regs, fc directly from accumulators ----
  float p0A = 0.0f, p1A = 0.0f, p0B = 0.0f, p1B = 0.0f;
#pragma unroll
  for (int ot = 0; ot < 2; ++ot) {
    int ob = (2 * w + ot) * 16 + q * 4;  // o base, 4 contiguous per lane
    float4 bv = *(const float4*)&bias2[ob];
#pragma unroll
    for (int nt = 0; nt < 2; ++nt) {
      int n = nt * 16 + l15;
      float4 w0 = *(const float4*)&fc_w[n * 128 + ob];
      float4 w1v = *(const float4*)&fc_w[4096 + n * 128 + ob];
      float hA0 = fmaxf(acc2A[ot][nt][0] + bv.x, 0.0f);
      float hA1 = fmaxf(acc2A[ot][nt][1] + bv.y, 0.0f);
      float hA2 = fmaxf(acc2A[ot][nt][2] + bv.z, 0.0f);
      float hA3 = fmaxf(acc2A[ot][nt][3] + bv.w, 0.0f);
      float hB0 = fmaxf(acc2B[ot][nt][0] + bv.x, 0.0f);
      float hB1 = fmaxf(acc2B[ot][nt][1] + bv.y, 0.0f);
      float hB2 = fmaxf(acc2B[ot][nt][2] + bv.z, 0.0f);
      float hB3 = fmaxf(acc2B[ot][nt][3] + bv.w, 0.0f);
      p0A = fmaf(hA0, w0.x, fmaf(hA1, w0.y, fmaf(hA2, w0.z, fmaf(hA3, w0.w, p0A))));
      p1A = fmaf(hA0, w1v.x, fmaf(hA1, w1v.y, fmaf(hA2, w1v.z, fmaf(hA3, w1v.w, p1A))));
      p0B = fmaf(hB0, w0.x, fmaf(hB1, w0.y, fmaf(hB2, w0.z, fmaf(hB3, w0.w, p0B))));
      p1B = fmaf(hB0, w1v.x, fmaf(hB1, w1v.y, fmaf(hB2, w1v.z, fmaf(hB3, w1v.w, p1B))));
    }
  }
#pragma unroll
  for (int off = 32; off >= 1; off >>= 1) {
    p0A += __shfl_xor(p0A, off);
    p1A += __shfl_xor(p1A, off);
    p0B += __shfl_xor(p0B, off);
    p1B += __shfl_xor(p1B, off);
  }
  if (lane == 0) {
    red[w * 4 + 0] = p0A;
    red[w * 4 + 1] = p1A;
    red[w * 4 + 2] = p0B;
    red[w * 4 + 3] = p1B;
  }
  __syncthreads();
  if (tid < 4) {
    float s = red[tid] + red[4 + tid] + red[8 + tid] + red[12 + tid] + fc_b[tid & 1];
    out[(b0 + (tid >> 1)) * 2 + (tid & 1)] = s;
  }
}

extern "C" void kernel_launch(void* const* d_in, const int* in_sizes, int n_in,
                              void* d_out, int out_size, void* d_ws, size_t ws_size,
                              hipStream_t stream) {
  const float* x        = (const float*)d_in[0];
  const float* adj      = (const float*)d_in[1];
  const float* adj_bias = (const float*)d_in[2];
  const float* w1       = (const float*)d_in[3];
  const float* b1       = (const float*)d_in[4];
  const float* w2       = (const float*)d_in[5];
  const float* b2       = (const float*)d_in[6];
  const float* fc_w     = (const float*)d_in[7];
  const float* fc_b     = (const float*)d_in[8];
  float* out = (float*)d_out;
  char* ws   = (char*)d_ws;

  prep_kernel<<<17, 256, 0, stream>>>(adj, adj_bias, w1, b1, w2, b2, ws);
  dgcnn_kernel<<<4096, 256, 0, stream>>>(x, ws, fc_w, fc_b, out);
}

// Round 6
// 173.779 us; speedup vs baseline: 1.1826x; 1.0272x over previous
//
#include <hip/hip_runtime.h>

typedef unsigned short u16;
typedef unsigned int u32;
typedef short bf16x8 __attribute__((ext_vector_type(8)));
typedef float f32x4 __attribute__((ext_vector_type(4)));
typedef u32 u32x4 __attribute__((ext_vector_type(4)));

#define MFMA16(a, b, c) __builtin_amdgcn_mfma_f32_16x16x32_bf16((a), (b), (c), 0, 0, 0)

__device__ __forceinline__ u16 f2bf(float f) {
  u32 u = __builtin_bit_cast(u32, f);
  u += 0x7FFFu + ((u >> 16) & 1u);
  return (u16)(u >> 16);
}
// packed f32x2 -> bf16x2, round-half-up (ties differ from RNE by <=1 ulp;
// absmax headroom 3x). 2 adds + shift + fused and/or (or v_perm) -- much
// cheaper than the RNE sequence. NOTE (R4 post-mortem): inline-asm
// v_cvt_pk_bf16_f32 produced NaN on this toolchain -- do NOT reintroduce it.
__device__ __forceinline__ u32 pk2bf(float a, float b) {
  u32 ua = __builtin_bit_cast(u32, a) + 0x8000u;
  u32 ub = __builtin_bit_cast(u32, b) + 0x8000u;
  return (ua >> 16) | (ub & 0xFFFF0000u);
}

// ws byte offsets
#define WS_MGF   0         // bf16 [8 jt][64 lane][8 j]      B-frags of M^T   (8192 B)
#define WS_WT1F  8192      // bf16 [8 ot][2 h][4 ks][64][8]  B-frags of Wp1   (65536 B)
#define WS_WT2F  73728     // bf16 [8 mt][4 h][4 ks][64][8]  A-frags of Wp2^T (131072 B)
#define WS_B1    204800    // f32 [128]  bias1 + T0-fold
#define WS_B2    205312    // f32 [128]  bias2 + T0-fold

// NOTE on element order (kc-permutation): within each 32-wide kc chunk, the
// fragment element at (reader lane q, elem j) holds channel
//   c_local = (j>>2)*16 + q*4 + (j&3)
// chosen so the G1 producer's 8 outputs per lane are CONTIGUOUS in LDS
// (one ds_write_b128). WT1F/WT2F below are built with the same order.
__global__ void prep_kernel(const float* __restrict__ adj,
                            const float* __restrict__ adj_bias,
                            const float* __restrict__ w1,
                            const float* __restrict__ b1,
                            const float* __restrict__ w2,
                            const float* __restrict__ b2,
                            char* __restrict__ ws) {
  const int tid = threadIdx.x;
  if (blockIdx.x == 0) {
    __shared__ float sa[1024], Ls[1024], L2s[1024], L3s[1024], sdre[32];
    float bias = adj_bias[0];
    for (int i = tid; i < 1024; i += 256) sa[i] = fmaxf(adj[i] + bias, 0.0f);
    __syncthreads();
    if (tid < 32) {
      float s = 0.0f;
      for (int c = 0; c < 32; ++c) s += sa[tid * 32 + c];
      sdre[tid] = 1.0f / sqrtf(s + 1e-5f);
    }
    __syncthreads();
    for (int i = tid; i < 1024; i += 256) {
      int n = i >> 5, c = i & 31;
      Ls[i] = (n == c ? 1.0f : 0.0f) - sdre[n] * sa[i] * sdre[c];
    }
    __syncthreads();
    for (int i = tid; i < 1024; i += 256) {
      int r = i >> 5, c = i & 31;
      float s = 0.0f;
      for (int m = 0; m < 32; ++m) s += Ls[r * 32 + m] * Ls[m * 32 + c];
      L2s[i] = s;
    }
    __syncthreads();
    for (int i = tid; i < 1024; i += 256) {
      int r = i >> 5, c = i & 31;
      float s = 0.0f;
      for (int m = 0; m < 32; ++m) s += L2s[r * 32 + m] * Ls[m * 32 + c];
      L3s[i] = s;
    }
    __syncthreads();
    // M stacked [128x32]: rows 0-31 I, 32-63 L, 64-95 2L^2-I, 96-127 4L^3-3L.
    // B-fragments of M^T: MGf[jt][lane][j] = M[col=jt*16+(lane&15)][k=(lane>>4)*8+j]
    u16* MGf = (u16*)(ws + WS_MGF);
    for (int i = tid; i < 4096; i += 256) {
      int jt = i >> 9, lane = (i >> 3) & 63, j = i & 7;
      int col = jt * 16 + (lane & 15);
      int k = ((lane >> 4) << 3) + j;
      int kk = col >> 5, np = col & 31;
      float v;
      if (kk == 0)      v = (np == k) ? 1.0f : 0.0f;
      else if (kk == 1) v = Ls[np * 32 + k];
      else if (kk == 2) v = 2.0f * L2s[np * 32 + k] - (np == k ? 1.0f : 0.0f);
      else              v = 4.0f * L3s[np * 32 + k] - 3.0f * Ls[np * 32 + k];
      MGf[i] = f2bf(v);
    }
    float* B1 = (float*)(ws + WS_B1);
    float* B2 = (float*)(ws + WS_B2);
    if (tid < 128) {
      float s = b1[tid];
      for (int c = 0; c < 60; ++c) s += w1[(c * 5) * 128 + tid];
      B1[tid] = s;
    } else {
      int o = tid - 128;
      float s = b2[o];
      for (int c = 0; c < 128; ++c) s += w2[(c * 5) * 128 + o];
      B2[o] = s;
    }
  } else {
    u16* WT1F = (u16*)(ws + WS_WT1F);
    u16* WT2F = (u16*)(ws + WS_WT2F);
    int g = (blockIdx.x - 1) * 256 + tid;
    // WT1F bits: j[0:3) lane[3:9) ks[9:11) h[11:12) ot[12:15)
    // element = w1 at kterm=ks, c = h*32 + (j>>2)*16 + q*4 + (j&3) (0 if c>=60),
    // o = ot*16+(lane&15)   [kc-permuted order]
    for (int i = g; i < 32768; i += 16 * 256) {
      int j = i & 7, lane = (i >> 3) & 63, ks = (i >> 9) & 3;
      int h = (i >> 11) & 1, ot = i >> 12;
      int q = lane >> 4;
      int c = h * 32 + ((j >> 2) << 4) + q * 4 + (j & 3);
      int o = ot * 16 + (lane & 15);
      WT1F[i] = (c < 60) ? f2bf(w1[(c * 5 + ks + 1) * 128 + o]) : (u16)0;
    }
    // WT2F bits: j[0:3) lane[3:9) ks[9:11) h[11:13) mt[13:16)
    // element = w2 at kterm=ks, c2 = h*32 + (j>>2)*16 + q*4 + (j&3),
    // o = mt*16+(lane&15)   [kc-permuted order]
    for (int i = g; i < 65536; i += 16 * 256) {
      int j = i & 7, lane = (i >> 3) & 63, ks = (i >> 9) & 3;
      int h = (i >> 11) & 3, mt = i >> 13;
      int q = lane >> 4;
      int c2 = h * 32 + ((j >> 2) << 4) + q * 4 + (j & 3);
      int o = mt * 16 + (lane & 15);
      WT2F[i] = f2bf(w2[(c2 * 5 + ks + 1) * 128 + o]);
    }
  }
}

// R5 base (2 batches/block, shared weight frags, bounds(256,4), Ht full-rank
// swizzle) + R6 software pipeline: G1-compute of chunk h runs IN THE SAME
// barrier region as einsum(h-1) (G1 output held in registers, Y written after
// the barrier). Same barrier count, single Y buffer; MFMA-heavy einsum and
// VALU-heavy pk2bf/G1 now co-schedule on separate pipes.
// LDS layouts (32768 B, 4 blocks/CU):
//   Xt [64 c][40] u16       pad-stride, 5120 B/batch
//   Ht [128 o][32] u16      slot swizzle ps = s ^ (l15&3) ^ (l15>>2)
//   Y  [32 np][128 kc] u16  16B-slot swizzle ps = s ^ (np&7); 8 KB/batch
//   Ht overlays Xt (Xt dead after layer-1 G1); red overlays Ht in epilogue.
__global__ __launch_bounds__(256, 4) void dgcnn_kernel(
    const float* __restrict__ x,
    const char* __restrict__ ws,
    const float* __restrict__ fc_w,
    const float* __restrict__ fc_b,
    float* __restrict__ out) {
  __shared__ __align__(16) char arena[32768];
  u16* XtA = (u16*)arena;             // 5120 B
  u16* XtB = (u16*)(arena + 5120);    // 5120 B
  u16* HtA = (u16*)arena;             // 8192 B (after Xt dead)
  u16* HtB = (u16*)(arena + 8192);    // 8192 B
  u16* YA  = (u16*)(arena + 16384);   // 8192 B
  u16* YB  = (u16*)(arena + 24576);   // 8192 B
  float* red = (float*)arena;         // epilogue overlay (Ht dead)

  const u16* MGf  = (const u16*)(ws + WS_MGF);
  const u16* WT1F = (const u16*)(ws + WS_WT1F);
  const u16* WT2F = (const u16*)(ws + WS_WT2F);
  const float* bias1 = (const float*)(ws + WS_B1);
  const float* bias2 = (const float*)(ws + WS_B2);

  const int tid = threadIdx.x;
  const int w = tid >> 6, lane = tid & 63;
  const int l15 = lane & 15, q = lane >> 4;
  const int b0 = blockIdx.x * 2;
  const f32x4 z4 = {0.0f, 0.0f, 0.0f, 0.0f};

  // M^T B-fragments: wave w covers M^T col tiles 2w, 2w+1 (k-term = w)
  bf16x8 mB0 = *(const bf16x8*)(MGf + ((2 * w + 0) * 64 + lane) * 8);
  bf16x8 mB1 = *(const bf16x8*)(MGf + ((2 * w + 1) * 64 + lane) * 8);

  // ---- stage x^T (both batches), coalesced float4 loads, b32 node-pair
  // writes (2-way banks = free). Threads with tc==60 write the zero rows.
  const float* xb = x + (size_t)b0 * 1920;
  {
    int tn = (tid & 15) * 2;   // node pair n, n+1
    int tc = (tid >> 4) * 4;   // channel quad c..c+3
    if (tc < 60) {
      float4 a0 = *(const float4*)(xb + tn * 60 + tc);
      float4 a1 = *(const float4*)(xb + tn * 60 + 60 + tc);
      float4 c0 = *(const float4*)(xb + 1920 + tn * 60 + tc);
      float4 c1 = *(const float4*)(xb + 1920 + tn * 60 + 60 + tc);
      *(u32*)&XtA[(tc + 0) * 40 + tn] = pk2bf(a0.x, a1.x);
      *(u32*)&XtA[(tc + 1) * 40 + tn] = pk2bf(a0.y, a1.y);
      *(u32*)&XtA[(tc + 2) * 40 + tn] = pk2bf(a0.z, a1.z);
      *(u32*)&XtA[(tc + 3) * 40 + tn] = pk2bf(a0.w, a1.w);
      *(u32*)&XtB[(tc + 0) * 40 + tn] = pk2bf(c0.x, c1.x);
      *(u32*)&XtB[(tc + 1) * 40 + tn] = pk2bf(c0.y, c1.y);
      *(u32*)&XtB[(tc + 2) * 40 + tn] = pk2bf(c0.z, c1.z);
      *(u32*)&XtB[(tc + 3) * 40 + tn] = pk2bf(c0.w, c1.w);
    } else {
#pragma unroll
      for (int j = 0; j < 4; ++j) {
        *(u32*)&XtA[(tc + j) * 40 + tn] = 0;
        *(u32*)&XtB[(tc + j) * 40 + tn] = 0;
      }
    }
  }
  __syncthreads();

  // G1 write swizzle: 16B slot (w*4+q) XOR'd with (np&7); same for both jtl.
  const int ysw_w = ((w * 4 + q) ^ (l15 & 7)) * 8;  // u16 units
  const int psr = (q ^ (l15 & 3) ^ (l15 >> 2)) * 8; // Ht read slot (layer 2)

  // G1 pipeline registers: [mtl][ct] as named vars (static indexing, rule #20)
  f32x4 gA00, gA01, gA10, gA11, gB00, gB01, gB10, gB11;

  // G1-compute from Xt (layer 1), chunk h -> g regs only (no LDS write)
  auto g1c_x = [&](int h) {
    int r0 = ((2 * h + 0) * 16 + l15) * 40 + q * 8;
    int r1 = ((2 * h + 1) * 16 + l15) * 40 + q * 8;
    bf16x8 aA0 = *(const bf16x8*)&XtA[r0];
    bf16x8 aA1 = *(const bf16x8*)&XtA[r1];
    bf16x8 aB0 = *(const bf16x8*)&XtB[r0];
    bf16x8 aB1 = *(const bf16x8*)&XtB[r1];
    gA00 = MFMA16(aA0, mB0, z4); gA01 = MFMA16(aA0, mB1, z4);
    gA10 = MFMA16(aA1, mB0, z4); gA11 = MFMA16(aA1, mB1, z4);
    gB00 = MFMA16(aB0, mB0, z4); gB01 = MFMA16(aB0, mB1, z4);
    gB10 = MFMA16(aB1, mB0, z4); gB11 = MFMA16(aB1, mB1, z4);
  };
  // G1-compute from Ht (layer 2), chunk h
  auto g1c_h = [&](int h) {
    int o20 = ((2 * h + 0) * 16 + l15) * 32 + psr;
    int o21 = ((2 * h + 1) * 16 + l15) * 32 + psr;
    bf16x8 aA0 = *(const bf16x8*)&HtA[o20];
    bf16x8 aA1 = *(const bf16x8*)&HtA[o21];
    bf16x8 aB0 = *(const bf16x8*)&HtB[o20];
    bf16x8 aB1 = *(const bf16x8*)&HtB[o21];
    gA00 = MFMA16(aA0, mB0, z4); gA01 = MFMA16(aA0, mB1, z4);
    gA10 = MFMA16(aA1, mB0, z4); gA11 = MFMA16(aA1, mB1, z4);
    gB00 = MFMA16(aB0, mB0, z4); gB01 = MFMA16(aB0, mB1, z4);
    gB10 = MFMA16(aB1, mB0, z4); gB11 = MFMA16(aB1, mB1, z4);
  };
  // pack + Y write of the held g regs (jtl=0 uses g*00/g*10, jtl=1 g*01/g*11)
  auto yw = [&]() {
    u32x4 vA = {pk2bf(gA00[0], gA00[1]), pk2bf(gA00[2], gA00[3]),
                pk2bf(gA10[0], gA10[1]), pk2bf(gA10[2], gA10[3])};
    u32x4 vB = {pk2bf(gB00[0], gB00[1]), pk2bf(gB00[2], gB00[3]),
                pk2bf(gB10[0], gB10[1]), pk2bf(gB10[2], gB10[3])};
    *(u32x4*)&YA[(0 * 16 + l15) * 128 + ysw_w] = vA;
    *(u32x4*)&YB[(0 * 16 + l15) * 128 + ysw_w] = vB;
    u32x4 wA = {pk2bf(gA01[0], gA01[1]), pk2bf(gA01[2], gA01[3]),
                pk2bf(gA11[0], gA11[1]), pk2bf(gA11[2], gA11[3])};
    u32x4 wB = {pk2bf(gB01[0], gB01[1]), pk2bf(gB01[2], gB01[3]),
                pk2bf(gB11[0], gB11[1]), pk2bf(gB11[2], gB11[3])};
    *(u32x4*)&YA[(1 * 16 + l15) * 128 + ysw_w] = wA;
    *(u32x4*)&YB[(1 * 16 + l15) * 128 + ysw_w] = wB;
  };

  // ---------------- layer 1: 2 kc-chunks, software-pipelined ----------------
  f32x4 acc1A[2][2] = {{z4, z4}, {z4, z4}};  // [nt][ot]
  f32x4 acc1B[2][2] = {{z4, z4}, {z4, z4}};
  auto einsum1 = [&](int h) {
#pragma unroll
    for (int ks = 0; ks < 4; ++ks) {
      const u16* wp = WT1F + (size_t)((((2 * w) * 2 + h) * 4 + ks) * 64 + lane) * 8;
      bf16x8 wfa = *(const bf16x8*)wp;
      bf16x8 wfb = *(const bf16x8*)(wp + 4096);  // ot+1
      int ysw = ((ks * 4 + q) ^ (l15 & 7)) * 8;
      bf16x8 a0A = *(const bf16x8*)&YA[l15 * 128 + ysw];
      bf16x8 a1A = *(const bf16x8*)&YA[(16 + l15) * 128 + ysw];
      bf16x8 a0B = *(const bf16x8*)&YB[l15 * 128 + ysw];
      bf16x8 a1B = *(const bf16x8*)&YB[(16 + l15) * 128 + ysw];
      acc1A[0][0] = MFMA16(a0A, wfa, acc1A[0][0]);
      acc1A[0][1] = MFMA16(a0A, wfb, acc1A[0][1]);
      acc1A[1][0] = MFMA16(a1A, wfa, acc1A[1][0]);
      acc1A[1][1] = MFMA16(a1A, wfb, acc1A[1][1]);
      acc1B[0][0] = MFMA16(a0B, wfa, acc1B[0][0]);
      acc1B[0][1] = MFMA16(a0B, wfb, acc1B[0][1]);
      acc1B[1][0] = MFMA16(a1B, wfa, acc1B[1][0]);
      acc1B[1][1] = MFMA16(a1B, wfb, acc1B[1][1]);
    }
  };

  g1c_x(0);
  yw();
  __syncthreads();           // Y(0) visible
  g1c_x(1);                  // overlaps einsum(0): separate pipes
  einsum1(0);
  __syncthreads();           // einsum(0) reads done
  yw();
  __syncthreads();           // Y(1) visible
  einsum1(1);

  // bias+relu -> Ht (Xt dead: all Xt reads preceded the pre-yw barriers)
#pragma unroll
  for (int ot = 0; ot < 2; ++ot) {
    int o = (2 * w + ot) * 16 + l15;
    float bv = bias1[o];
#pragma unroll
    for (int mt = 0; mt < 2; ++mt) {
      // logical n-slot s = mt*2 + (q>>1); physical = s ^ (l15&3) ^ (l15>>2)
      int ps = (mt * 2 + (q >> 1)) ^ (l15 & 3) ^ (l15 >> 2);
      int idx = o * 32 + ps * 8 + (q & 1) * 4;
      uint2 vA, vB;
      vA.x = pk2bf(fmaxf(acc1A[mt][ot][0] + bv, 0.0f), fmaxf(acc1A[mt][ot][1] + bv, 0.0f));
      vA.y = pk2bf(fmaxf(acc1A[mt][ot][2] + bv, 0.0f), fmaxf(acc1A[mt][ot][3] + bv, 0.0f));
      vB.x = pk2bf(fmaxf(acc1B[mt][ot][0] + bv, 0.0f), fmaxf(acc1B[mt][ot][1] + bv, 0.0f));
      vB.y = pk2bf(fmaxf(acc1B[mt][ot][2] + bv, 0.0f), fmaxf(acc1B[mt][ot][3] + bv, 0.0f));
      *(uint2*)&HtA[idx] = vA;
      *(uint2*)&HtB[idx] = vB;
    }
  }
  __syncthreads();           // Ht visible; also fences einsum1(1) Y-reads

  // ---------------- layer 2: 4 kc-chunks, software-pipelined ----------------
  f32x4 acc2A[2][2] = {{z4, z4}, {z4, z4}};  // [ot][nt]
  f32x4 acc2B[2][2] = {{z4, z4}, {z4, z4}};
  auto einsum2 = [&](int h) {
#pragma unroll
    for (int ks = 0; ks < 4; ++ks) {
      const u16* wp = WT2F + (size_t)((((2 * w) * 4 + h) * 4 + ks) * 64 + lane) * 8;
      bf16x8 wfa = *(const bf16x8*)wp;
      bf16x8 wfb = *(const bf16x8*)(wp + 8192);  // mt+1
      int ysw = ((ks * 4 + q) ^ (l15 & 7)) * 8;
      bf16x8 by0A = *(const bf16x8*)&YA[l15 * 128 + ysw];
      bf16x8 by1A = *(const bf16x8*)&YA[(16 + l15) * 128 + ysw];
      bf16x8 by0B = *(const bf16x8*)&YB[l15 * 128 + ysw];
      bf16x8 by1B = *(const bf16x8*)&YB[(16 + l15) * 128 + ysw];
      acc2A[0][0] = MFMA16(wfa, by0A, acc2A[0][0]);
      acc2A[0][1] = MFMA16(wfa, by1A, acc2A[0][1]);
      acc2A[1][0] = MFMA16(wfb, by0A, acc2A[1][0]);
      acc2A[1][1] = MFMA16(wfb, by1A, acc2A[1][1]);
      acc2B[0][0] = MFMA16(wfa, by0B, acc2B[0][0]);
      acc2B[0][1] = MFMA16(wfa, by1B, acc2B[0][1]);
      acc2B[1][0] = MFMA16(wfb, by0B, acc2B[1][0]);
      acc2B[1][1] = MFMA16(wfb, by1B, acc2B[1][1]);
    }
  };

  g1c_h(0);
  yw();                      // overwrites Y last read by einsum1(1) -- fenced
  __syncthreads();           // by the post-Ht barrier above; Y(0) visible now
#pragma unroll
  for (int h = 1; h < 4; ++h) {
    g1c_h(h);                // overlaps einsum2(h-1)
    einsum2(h - 1);
    __syncthreads();         // einsum2(h-1) reads done
    yw();
    __syncthreads();         // Y(h) visible
  }
  einsum2(3);

  // ---- epilogue: bias2+relu in regs, fc directly from accumulators ----
  float p0A = 0.0f, p1A = 0.0f, p0B = 0.0f, p1B = 0.0f;
#pragma unroll
  for (int ot = 0; ot < 2; ++ot) {
    int ob = (2 * w + ot) * 16 + q * 4;  // o base, 4 contiguous per lane
    float4 bv = *(const float4*)&bias2[ob];
#pragma unroll
    for (int nt = 0; nt < 2; ++nt) {
      int n = nt * 16 + l15;
      float4 w0 = *(const float4*)&fc_w[n * 128 + ob];
      float4 w1v = *(const float4*)&fc_w[4096 + n * 128 + ob];
      float hA0 = fmaxf(acc2A[ot][nt][0] + bv.x, 0.0f);
      float hA1 = fmaxf(acc2A[ot][nt][1] + bv.y, 0.0f);
      float hA2 = fmaxf(acc2A[ot][nt][2] + bv.z, 0.0f);
      float hA3 = fmaxf(acc2A[ot][nt][3] + bv.w, 0.0f);
      float hB0 = fmaxf(acc2B[ot][nt][0] + bv.x, 0.0f);
      float hB1 = fmaxf(acc2B[ot][nt][1] + bv.y, 0.0f);
      float hB2 = fmaxf(acc2B[ot][nt][2] + bv.z, 0.0f);
      float hB3 = fmaxf(acc2B[ot][nt][3] + bv.w, 0.0f);
      p0A = fmaf(hA0, w0.x, fmaf(hA1, w0.y, fmaf(hA2, w0.z, fmaf(hA3, w0.w, p0A))));
      p1A = fmaf(hA0, w1v.x, fmaf(hA1, w1v.y, fmaf(hA2, w1v.z, fmaf(hA3, w1v.w, p1A))));
      p0B = fmaf(hB0, w0.x, fmaf(hB1, w0.y, fmaf(hB2, w0.z, fmaf(hB3, w0.w, p0B))));
      p1B = fmaf(hB0, w1v.x, fmaf(hB1, w1v.y, fmaf(hB2, w1v.z, fmaf(hB3, w1v.w, p1B))));
    }
  }
#pragma unroll
  for (int off = 32; off >= 1; off >>= 1) {
    p0A += __shfl_xor(p0A, off);
    p1A += __shfl_xor(p1A, off);
    p0B += __shfl_xor(p0B, off);
    p1B += __shfl_xor(p1B, off);
  }
  if (lane == 0) {
    red[w * 4 + 0] = p0A;
    red[w * 4 + 1] = p1A;
    red[w * 4 + 2] = p0B;
    red[w * 4 + 3] = p1B;
  }
  __syncthreads();
  if (tid < 4) {
    float s = red[tid] + red[4 + tid] + red[8 + tid] + red[12 + tid] + fc_b[tid & 1];
    out[(b0 + (tid >> 1)) * 2 + (tid & 1)] = s;
  }
}

extern "C" void kernel_launch(void* const* d_in, const int* in_sizes, int n_in,
                              void* d_out, int out_size, void* d_ws, size_t ws_size,
                              hipStream_t stream) {
  const float* x        = (const float*)d_in[0];
  const float* adj      = (const float*)d_in[1];
  const float* adj_bias = (const float*)d_in[2];
  const float* w1       = (const float*)d_in[3];
  const float* b1       = (const float*)d_in[4];
  const float* w2       = (const float*)d_in[5];
  const float* b2       = (const float*)d_in[6];
  const float* fc_w     = (const float*)d_in[7];
  const float* fc_b     = (const float*)d_in[8];
  float* out = (float*)d_out;
  char* ws   = (char*)d_ws;

  prep_kernel<<<17, 256, 0, stream>>>(adj, adj_bias, w1, b1, w2, b2, ws);
  dgcnn_kernel<<<4096, 256, 0, stream>>>(x, ws, fc_w, fc_b, out);
}